// Round 4
// baseline (806.844 us; speedup 1.0000x reference)
//
#include <hip/hip_runtime.h>
#include <cmath>

#define NUM_LEVELS 16
#define GRID_CH 66
#define BLOCK 256
#define NSAMP 262144

struct LevelP { int offset; int res_eff; int use_hash; float scale; };

static LevelP g_levels[NUM_LEVELS];
static bool init_levels() {
    long long off = 0;
    const double S = std::log2(2048.0 / 16.0) / 15.0;   // 7/15
    for (int l = 0; l < NUM_LEVELS; ++l) {
        double scale = std::exp2((double)l * S) * 16.0 - 1.0;
        int resolution = (int)std::ceil(scale) + 1;
        int res_eff = resolution + 1;                    // ALIGN_CORNERS = False
        long long cube = (long long)res_eff * res_eff * res_eff;
        long long n = cube < 131072 ? cube : 131072;
        n = ((n + 7) / 8) * 8;
        g_levels[l].offset   = (int)off;
        g_levels[l].res_eff  = res_eff;
        g_levels[l].use_hash = (cube > n) ? 1 : 0;
        g_levels[l].scale    = (float)scale;
        off += n;
    }
    return true;
}
static bool g_inited = init_levels();

// 8-byte pair, 4-byte alignment (channel index may be odd).
struct __attribute__((packed, aligned(4))) F2 { float x, y; };

// One level per launch: kernel boundaries are hard grid-wide barriers, so the
// level's 34.6 MB table is the only hot data during the launch -> L3-resident,
// and the ~16x/line reuse stops hitting HBM.
__global__ __launch_bounds__(BLOCK) void tge_level(
    const float* __restrict__ inputs,   // [B,3]
    const float* __restrict__ tri,      // [B,8]
    const float* __restrict__ tbl,      // emb + level_offset*66
    float* __restrict__ dst,            // scratch[l] (stride 2) or out+2l (stride 32)
    int dstStride,
    float scale, int R, int use_hash)
{
    const int i = blockIdx.x * BLOCK + threadIdx.x;    // sample

    const float x = inputs[i * 3 + 0];
    const float y = inputs[i * 3 + 1];
    const float z = inputs[i * 3 + 2];
    const float4 t0 = *reinterpret_cast<const float4*>(tri + (size_t)i * 8);
    const float4 t1 = *reinterpret_cast<const float4*>(tri + (size_t)i * 8 + 4);
    const float wa0 = t0.x, wb0 = t0.z, wa1 = t1.x, wb1 = t1.z;
    const int   ia0 = (int)t0.y, ia1 = (int)t1.y;

    // ib == (ia+1) % 66: one float2 covers (va,vb) except the wrap case.
    const int  base0 = ia0 < 64 ? ia0 : 64;   // float2 never reads past ch 65
    const int  base1 = ia1 < 64 ? ia1 : 64;
    const bool hi0 = (ia0 == 65);
    const bool hi1 = (ia1 == 65);

    const float px = x * scale + 0.5f;
    const float py = y * scale + 0.5f;
    const float pz = z * scale + 0.5f;
    const float fx = floorf(px), fy = floorf(py), fz = floorf(pz);
    const float rx = px - fx, ry = py - fy, rz = pz - fz;
    const unsigned ux = (unsigned)fx, uy = (unsigned)fy, uz = (unsigned)fz;

    unsigned hx0, hx1, hy0, hy1, hz0, hz1;
    if (use_hash) {
        hx0 = ux;                   hx1 = ux + 1u;                     // prime 1
        hy0 = uy * 2654435761u;     hy1 = (uy + 1u) * 2654435761u;
        hz0 = uz * 805459861u;      hz1 = (uz + 1u) * 805459861u;
    } else {
        hx0 = ux;                   hx1 = ux + 1u;
        hy0 = uy * (unsigned)R;     hy1 = (uy + 1u) * (unsigned)R;
        hz0 = uz * (unsigned)(R*R); hz1 = (uz + 1u) * (unsigned)(R*R);
    }

    const float w0x = 1.f - rx, w1x = rx;
    const float w0y = 1.f - ry, w1y = ry;
    const float w0z = 1.f - rz, w1z = rz;

    float acc0 = 0.f, acc1 = 0.f;
    #pragma unroll
    for (int c = 0; c < 8; ++c) {
        const unsigned a = (c & 1) ? hx1 : hx0;
        const unsigned b = (c & 2) ? hy1 : hy0;
        const unsigned d = (c & 4) ? hz1 : hz0;
        const unsigned idx = use_hash ? ((a ^ b ^ d) & 131071u) : (a + b + d);
        const float* rowp = tbl + (size_t)idx * GRID_CH;

        const F2 pa0 = *reinterpret_cast<const F2*>(rowp + base0);
        const F2 pa1 = *reinterpret_cast<const F2*>(rowp + base1);
        const float va0 = hi0 ? pa0.y : pa0.x;
        const float va1 = hi1 ? pa1.y : pa1.x;
        float vb0 = pa0.y, vb1 = pa1.y;
        if (hi0) vb0 = rowp[0];               // wrap: exec-masked rare load
        if (hi1) vb1 = rowp[0];

        const float wx = (c & 1) ? w1x : w0x;
        const float wy = (c & 2) ? w1y : w0y;
        const float wz = (c & 4) ? w1z : w0z;
        const float w = wx * wy * wz;
        acc0 += w * (wa0 * va0 + wb0 * vb0);
        acc1 += w * (wa1 * va1 + wb1 * vb1);
    }

    *reinterpret_cast<float2*>(dst + (size_t)i * dstStride) = make_float2(acc0, acc1);
}

// scratch[16][B][2] -> out[B][32], both sides coalesced via LDS tile.
__global__ __launch_bounds__(256) void tge_transpose(
    const float* __restrict__ scr, float* __restrict__ out, int B)
{
    __shared__ float tile[64][33];
    const int t  = threadIdx.x;
    const int s0 = blockIdx.x * 64;          // 64 samples per block
    const int sl = t & 63;
    const int lq = t >> 6;                   // 0..3

    #pragma unroll
    for (int p = 0; p < 4; ++p) {
        const int l = p * 4 + lq;
        const float2 v = *reinterpret_cast<const float2*>(
            scr + ((size_t)l * B + s0 + sl) * 2);
        tile[sl][2 * l]     = v.x;
        tile[sl][2 * l + 1] = v.y;
    }
    __syncthreads();

    #pragma unroll
    for (int k = 0; k < 2; ++k) {
        const int g = t + k * 256;           // float4 index 0..511
        const int s = g >> 3;
        const int c = (g & 7) * 4;
        const float4 v = make_float4(tile[s][c], tile[s][c + 1],
                                     tile[s][c + 2], tile[s][c + 3]);
        *reinterpret_cast<float4*>(out + ((size_t)(s0 + s)) * 32 + c) = v;
    }
}

extern "C" void kernel_launch(void* const* d_in, const int* in_sizes, int n_in,
                              void* d_out, int out_size, void* d_ws, size_t ws_size,
                              hipStream_t stream) {
    const float* inputs = (const float*)d_in[0];
    const float* tri    = (const float*)d_in[1];
    const float* emb    = (const float*)d_in[2];
    float* out          = (float*)d_out;
    float* ws           = (float*)d_ws;

    const int B = in_sizes[0] / 3;           // 262144
    const size_t need = (size_t)NUM_LEVELS * B * 2 * sizeof(float);
    const bool use_ws = ws_size >= need;

    dim3 grid(B / BLOCK, 1, 1);
    for (int l = 0; l < NUM_LEVELS; ++l) {
        const LevelP& P = g_levels[l];
        float* dst      = use_ws ? (ws + (size_t)l * B * 2) : (out + 2 * l);
        const int strid = use_ws ? 2 : 32;
        tge_level<<<grid, BLOCK, 0, stream>>>(
            inputs, tri, emb + (size_t)P.offset * GRID_CH,
            dst, strid, P.scale, P.res_eff, P.use_hash);
    }
    if (use_ws) {
        tge_transpose<<<dim3(B / 64, 1, 1), 256, 0, stream>>>(ws, out, B);
    }
}

// Round 6
// 710.930 us; speedup vs baseline: 1.1349x; 1.1349x over previous
//
#include <hip/hip_runtime.h>
#include <cmath>

#define NUM_LEVELS 16
#define GRID_CH 66
#define BLOCK 256
#define NGRP 8

typedef float float4n __attribute__((ext_vector_type(4)));
typedef float float2n __attribute__((ext_vector_type(2)));

struct LevelP { int offset; int res_eff; int use_hash; int hsize; float scale; };

static LevelP g_levels[NUM_LEVELS];
static bool init_levels() {
    long long off = 0;
    const double S = std::log2(2048.0 / 16.0) / 15.0;   // 7/15
    for (int l = 0; l < NUM_LEVELS; ++l) {
        double scale = std::exp2((double)l * S) * 16.0 - 1.0;
        int resolution = (int)std::ceil(scale) + 1;
        int res_eff = resolution + 1;                    // ALIGN_CORNERS = False
        long long cube = (long long)res_eff * res_eff * res_eff;
        long long n = cube < 131072 ? cube : 131072;
        n = ((n + 7) / 8) * 8;
        g_levels[l].offset   = (int)off;
        g_levels[l].res_eff  = res_eff;
        g_levels[l].use_hash = (cube > n) ? 1 : 0;
        g_levels[l].hsize    = (int)n;
        g_levels[l].scale    = (float)scale;
        off += n;
    }
    return true;
}
static bool g_inited = init_levels();

// 8-byte pair, 4-byte alignment (channel index may be odd).
struct __attribute__((packed, aligned(4))) F2 { float x, y; };

// Pack temporal_row_index: wab[i] = {wa0, wb0, wa1, wb1}, ias[i] = ia0 | ia1<<8.
__global__ __launch_bounds__(BLOCK) void tge_prep(
    const float* __restrict__ tri, float* __restrict__ wab,
    unsigned* __restrict__ ias)
{
    const int i = blockIdx.x * BLOCK + threadIdx.x;
    const float4 t0 = *reinterpret_cast<const float4*>(tri + (size_t)i * 8);
    const float4 t1 = *reinterpret_cast<const float4*>(tri + (size_t)i * 8 + 4);
    float4n w; w.x = t0.x; w.y = t0.z; w.z = t1.x; w.w = t1.z;
    *reinterpret_cast<float4n*>(wab + (size_t)i * 4) = w;
    ias[i] = (unsigned)(int)t0.y | ((unsigned)(int)t1.y << 8);
}

__device__ inline void corner_indices(
    float x, float y, float z, float scale, int R, int use_hash,
    unsigned& hx0, unsigned& hx1, unsigned& hy0, unsigned& hy1,
    unsigned& hz0, unsigned& hz1,
    float& rx, float& ry, float& rz)
{
    const float px = x * scale + 0.5f;
    const float py = y * scale + 0.5f;
    const float pz = z * scale + 0.5f;
    const float fx = floorf(px), fy = floorf(py), fz = floorf(pz);
    rx = px - fx; ry = py - fy; rz = pz - fz;
    const unsigned ux = (unsigned)fx, uy = (unsigned)fy, uz = (unsigned)fz;
    if (use_hash) {
        hx0 = ux;                   hx1 = ux + 1u;                     // prime 1
        hy0 = uy * 2654435761u;     hy1 = (uy + 1u) * 2654435761u;
        hz0 = uz * 805459861u;      hz1 = (uz + 1u) * 805459861u;
    } else {
        hx0 = ux;                   hx1 = ux + 1u;
        hy0 = uy * (unsigned)R;     hy1 = (uy + 1u) * (unsigned)R;
        hz0 = uz * (unsigned)(R*R); hz1 = (uz + 1u) * (unsigned)(R*R);
    }
}

// Sliced gather: blocks with (blockIdx.x & 7)==g gather only corners whose idx
// falls in table slice g (~4.3 MB, L2-sized). Round-robin dispatch puts group g
// on XCD g, so all ~16 visits to a row hit the same L2 (perf-only assumption).
// blockIdx.y==1 slab reduces the PREVIOUS level's partials (ping-pong buffers).
__global__ __launch_bounds__(BLOCK) void tge_gather(
    const float* __restrict__ inputs, const float* __restrict__ wab,
    const unsigned* __restrict__ ias, const float* __restrict__ tbl,
    float* __restrict__ part,                  // [NGRP][B] float2
    const float2* __restrict__ partPrev,       // [NGRP][B] (prev level)
    float2* __restrict__ accPrev,              // acc[l-1] (B float2)
    float scale, int R, int use_hash, int sliceSize, int B)
{
    if (blockIdx.y != 0) {                     // reduce slab (prev level)
        const int s = blockIdx.x * BLOCK + threadIdx.x;
        if (s < B) {
            float a0 = 0.f, a1 = 0.f;
            #pragma unroll
            for (int g = 0; g < NGRP; ++g) {
                const float2 v = partPrev[(size_t)g * B + s];
                a0 += v.x; a1 += v.y;
            }
            accPrev[s] = make_float2(a0, a1);
        }
        return;
    }

    const int g = blockIdx.x & (NGRP - 1);
    const int i = (blockIdx.x >> 3) * BLOCK + threadIdx.x;

    // Non-temporal scan loads: don't evict the table slice from L2.
    const float x = __builtin_nontemporal_load(inputs + (size_t)i * 3 + 0);
    const float y = __builtin_nontemporal_load(inputs + (size_t)i * 3 + 1);
    const float z = __builtin_nontemporal_load(inputs + (size_t)i * 3 + 2);
    const float4n w4 = __builtin_nontemporal_load(
        reinterpret_cast<const float4n*>(wab + (size_t)i * 4));
    const unsigned iap = __builtin_nontemporal_load(ias + i);
    const int  ia0 = (int)(iap & 0xffu), ia1 = (int)((iap >> 8) & 0xffu);
    const int  base0 = ia0 < 64 ? ia0 : 64;
    const int  base1 = ia1 < 64 ? ia1 : 64;
    const bool hi0 = (ia0 == 65), hi1 = (ia1 == 65);

    unsigned hx0, hx1, hy0, hy1, hz0, hz1; float rx, ry, rz;
    corner_indices(x, y, z, scale, R, use_hash, hx0, hx1, hy0, hy1, hz0, hz1, rx, ry, rz);

    const float w0x = 1.f - rx, w1x = rx;
    const float w0y = 1.f - ry, w1y = ry;
    const float w0z = 1.f - rz, w1z = rz;

    const unsigned lo = (unsigned)(g * sliceSize);
    const unsigned hicut = lo + (unsigned)sliceSize;

    float acc0 = 0.f, acc1 = 0.f;
    #pragma unroll
    for (int c = 0; c < 8; ++c) {
        const unsigned a = (c & 1) ? hx1 : hx0;
        const unsigned b = (c & 2) ? hy1 : hy0;
        const unsigned d = (c & 4) ? hz1 : hz0;
        const unsigned idx = use_hash ? ((a ^ b ^ d) & 131071u) : (a + b + d);
        if (idx >= lo && idx < hicut) {        // exec-masked: ~1/8 of lanes
            const float* rowp = tbl + (size_t)idx * GRID_CH;
            const F2 pa0 = *reinterpret_cast<const F2*>(rowp + base0);
            const F2 pa1 = *reinterpret_cast<const F2*>(rowp + base1);
            const float va0 = hi0 ? pa0.y : pa0.x;
            const float va1 = hi1 ? pa1.y : pa1.x;
            float vb0 = pa0.y, vb1 = pa1.y;
            if (hi0) vb0 = rowp[0];
            if (hi1) vb1 = rowp[0];
            const float wx = (c & 1) ? w1x : w0x;
            const float wy = (c & 2) ? w1y : w0y;
            const float wz = (c & 4) ? w1z : w0z;
            const float w = wx * wy * wz;
            acc0 += w * (w4.x * va0 + w4.y * vb0);
            acc1 += w * (w4.z * va1 + w4.w * vb1);
        }
    }
    float2n r; r.x = acc0; r.y = acc1;
    __builtin_nontemporal_store(
        r, reinterpret_cast<float2n*>(part + ((size_t)g * B + i) * 2));
}

// Standalone reduce (used for the last level).
__global__ __launch_bounds__(BLOCK) void tge_reduce(
    const float2* __restrict__ partPrev, float2* __restrict__ accPrev, int B)
{
    const int s = blockIdx.x * BLOCK + threadIdx.x;
    if (s < B) {
        float a0 = 0.f, a1 = 0.f;
        #pragma unroll
        for (int g = 0; g < NGRP; ++g) {
            const float2 v = partPrev[(size_t)g * B + s];
            a0 += v.x; a1 += v.y;
        }
        accPrev[s] = make_float2(a0, a1);
    }
}

// Simple per-level path: levels with L2-resident tables (and ws fallback).
__global__ __launch_bounds__(BLOCK) void tge_level(
    const float* __restrict__ inputs, const float* __restrict__ tri,
    const float* __restrict__ tbl, float* __restrict__ dst, int dstStride,
    float scale, int R, int use_hash)
{
    const int i = blockIdx.x * BLOCK + threadIdx.x;

    const float x = inputs[i * 3 + 0];
    const float y = inputs[i * 3 + 1];
    const float z = inputs[i * 3 + 2];
    const float4 t0 = *reinterpret_cast<const float4*>(tri + (size_t)i * 8);
    const float4 t1 = *reinterpret_cast<const float4*>(tri + (size_t)i * 8 + 4);
    const float wa0 = t0.x, wb0 = t0.z, wa1 = t1.x, wb1 = t1.z;
    const int   ia0 = (int)t0.y, ia1 = (int)t1.y;
    const int  base0 = ia0 < 64 ? ia0 : 64;
    const int  base1 = ia1 < 64 ? ia1 : 64;
    const bool hi0 = (ia0 == 65), hi1 = (ia1 == 65);

    unsigned hx0, hx1, hy0, hy1, hz0, hz1; float rx, ry, rz;
    corner_indices(x, y, z, scale, R, use_hash, hx0, hx1, hy0, hy1, hz0, hz1, rx, ry, rz);

    const float w0x = 1.f - rx, w1x = rx;
    const float w0y = 1.f - ry, w1y = ry;
    const float w0z = 1.f - rz, w1z = rz;

    float acc0 = 0.f, acc1 = 0.f;
    #pragma unroll
    for (int c = 0; c < 8; ++c) {
        const unsigned a = (c & 1) ? hx1 : hx0;
        const unsigned b = (c & 2) ? hy1 : hy0;
        const unsigned d = (c & 4) ? hz1 : hz0;
        const unsigned idx = use_hash ? ((a ^ b ^ d) & 131071u) : (a + b + d);
        const float* rowp = tbl + (size_t)idx * GRID_CH;
        const F2 pa0 = *reinterpret_cast<const F2*>(rowp + base0);
        const F2 pa1 = *reinterpret_cast<const F2*>(rowp + base1);
        const float va0 = hi0 ? pa0.y : pa0.x;
        const float va1 = hi1 ? pa1.y : pa1.x;
        float vb0 = pa0.y, vb1 = pa1.y;
        if (hi0) vb0 = rowp[0];
        if (hi1) vb1 = rowp[0];
        const float wx = (c & 1) ? w1x : w0x;
        const float wy = (c & 2) ? w1y : w0y;
        const float wz = (c & 4) ? w1z : w0z;
        const float w = wx * wy * wz;
        acc0 += w * (wa0 * va0 + wb0 * vb0);
        acc1 += w * (wa1 * va1 + wb1 * vb1);
    }
    *reinterpret_cast<float2*>(dst + (size_t)i * dstStride) = make_float2(acc0, acc1);
}

// acc[16][B][2] -> out[B][32], both sides coalesced via LDS tile.
__global__ __launch_bounds__(256) void tge_transpose(
    const float* __restrict__ scr, float* __restrict__ out, int B)
{
    __shared__ float tile[64][33];
    const int t  = threadIdx.x;
    const int s0 = blockIdx.x * 64;
    const int sl = t & 63;
    const int lq = t >> 6;

    #pragma unroll
    for (int p = 0; p < 4; ++p) {
        const int l = p * 4 + lq;
        const float2 v = *reinterpret_cast<const float2*>(
            scr + ((size_t)l * B + s0 + sl) * 2);
        tile[sl][2 * l]     = v.x;
        tile[sl][2 * l + 1] = v.y;
    }
    __syncthreads();

    #pragma unroll
    for (int k = 0; k < 2; ++k) {
        const int g = t + k * 256;
        const int s = g >> 3;
        const int c = (g & 7) * 4;
        const float4 v = make_float4(tile[s][c], tile[s][c + 1],
                                     tile[s][c + 2], tile[s][c + 3]);
        *reinterpret_cast<float4*>(out + ((size_t)(s0 + s)) * 32 + c) = v;
    }
}

extern "C" void kernel_launch(void* const* d_in, const int* in_sizes, int n_in,
                              void* d_out, int out_size, void* d_ws, size_t ws_size,
                              hipStream_t stream) {
    const float* inputs = (const float*)d_in[0];
    const float* tri    = (const float*)d_in[1];
    const float* emb    = (const float*)d_in[2];
    float* out          = (float*)d_out;

    const int B = in_sizes[0] / 3;           // 262144

    // ws layout: acc[16][B] float2 | part0[8][B] float2 | part1[8][B] float2
    //            | wab[B] float4 | ias[B] u32
    float2*   acc   = (float2*)d_ws;
    float2*   part0 = acc + (size_t)16 * B;
    float2*   part1 = part0 + (size_t)NGRP * B;
    float*    wab   = (float*)(part1 + (size_t)NGRP * B);
    unsigned* ias   = (unsigned*)(wab + (size_t)B * 4);
    const size_t need = (size_t)((char*)(ias + B) - (char*)d_ws);

    if (ws_size < need) {                    // fallback: R4-style direct path
        for (int l = 0; l < NUM_LEVELS; ++l) {
            const LevelP& P = g_levels[l];
            tge_level<<<dim3(B / BLOCK), BLOCK, 0, stream>>>(
                inputs, tri, emb + (size_t)P.offset * GRID_CH,
                out + 2 * l, 32, P.scale, P.res_eff, P.use_hash);
        }
        return;
    }

    tge_prep<<<dim3(B / BLOCK), BLOCK, 0, stream>>>(tri, wab, ias);

    const int FIRST_SLICED = 2;              // levels 0-1: tables <= 2.8 MB
    for (int l = 0; l < FIRST_SLICED; ++l) {
        const LevelP& P = g_levels[l];
        tge_level<<<dim3(B / BLOCK), BLOCK, 0, stream>>>(
            inputs, tri, emb + (size_t)P.offset * GRID_CH,
            (float*)(acc + (size_t)l * B), 2, P.scale, P.res_eff, P.use_hash);
    }

    float2* parts[2] = { part0, part1 };
    for (int l = FIRST_SLICED; l < NUM_LEVELS; ++l) {
        const LevelP& P = g_levels[l];
        const bool carry = (l > FIRST_SLICED);          // reduce level l-1
        float2* partCur  = parts[l & 1];
        float2* partPrev = parts[(l & 1) ^ 1];
        dim3 grid(NGRP * (B / BLOCK), carry ? 2 : 1, 1);
        tge_gather<<<grid, BLOCK, 0, stream>>>(
            inputs, wab, ias, emb + (size_t)P.offset * GRID_CH,
            (float*)partCur,
            carry ? partPrev : nullptr,
            carry ? acc + (size_t)(l - 1) * B : nullptr,
            P.scale, P.res_eff, P.use_hash,
            (P.hsize + NGRP - 1) / NGRP, B);
    }
    tge_reduce<<<dim3(B / BLOCK), BLOCK, 0, stream>>>(
        parts[(NUM_LEVELS - 1) & 1], acc + (size_t)(NUM_LEVELS - 1) * B, B);

    tge_transpose<<<dim3(B / 64), 256, 0, stream>>>((const float*)acc, out, B);
}